// Round 6
// baseline (658.029 us; speedup 1.0000x reference)
//
#include <hip/hip_runtime.h>
#include <hip/hip_bf16.h>

#define HID 128
#define NGRAPH 512
#define IN_DIM 384

__device__ __forceinline__ float bf2f(unsigned int u16) {
    union { float f; unsigned int i; } x;
    x.i = u16 << 16;
    return x.f;
}
__device__ __forceinline__ unsigned short f2bf(float f) {
    union { float f; unsigned int i; } x;
    x.f = f;
    unsigned int r = (x.i + 0x7FFFu + ((x.i >> 16) & 1u)) >> 16;
    return (unsigned short)r;
}

// ---------------- degree ----------------
__global__ void deg_kernel(const int* __restrict__ dst, int* __restrict__ deg, int E) {
    int e = blockIdx.x * blockDim.x + threadIdx.x;
    if (e < E) atomicAdd(&deg[dst[e]], 1);
}

__global__ void dis_kernel(const int* __restrict__ deg, float* __restrict__ dis, int n) {
    int v = blockIdx.x * blockDim.x + threadIdx.x;
    if (v < n) dis[v] = rsqrtf((float)(deg[v] + 1));  // +1 = self-loop
}

// ---------------- exclusive scan of deg -> row_start ----------------
__global__ __launch_bounds__(256) void scan_part(const int* __restrict__ deg, int* __restrict__ row,
                                                 int* __restrict__ blockSums, int n) {
    __shared__ int ts[256];
    const int b = blockIdx.x, t = threadIdx.x;
    const int base = b * 1024 + t * 4;
    int v0 = (base + 0 < n) ? deg[base + 0] : 0;
    int v1 = (base + 1 < n) ? deg[base + 1] : 0;
    int v2 = (base + 2 < n) ? deg[base + 2] : 0;
    int v3 = (base + 3 < n) ? deg[base + 3] : 0;
    const int s = v0 + v1 + v2 + v3;
    ts[t] = s;
    __syncthreads();
    for (int off = 1; off < 256; off <<= 1) {
        int x = (t >= off) ? ts[t - off] : 0;
        __syncthreads();
        ts[t] += x;
        __syncthreads();
    }
    int p = ts[t] - s;
    if (base + 0 < n) { row[base + 0] = p; p += v0; }
    if (base + 1 < n) { row[base + 1] = p; p += v1; }
    if (base + 2 < n) { row[base + 2] = p; p += v2; }
    if (base + 3 < n) { row[base + 3] = p; }
    if (t == 255) blockSums[b] = ts[255];
}

__global__ void scan_tops(int* __restrict__ blockSums, int nb) {
    if (threadIdx.x == 0 && blockIdx.x == 0) {
        int acc = 0;
        for (int i = 0; i < nb; i++) { int v = blockSums[i]; blockSums[i] = acc; acc += v; }
    }
}

__global__ __launch_bounds__(256) void scan_add(int* __restrict__ row, int* __restrict__ cursor,
                                                const int* __restrict__ blockSums, int n, int E) {
    const int b = blockIdx.x, t = threadIdx.x;
    const int off = blockSums[b];
    const int base = b * 1024 + t * 4;
#pragma unroll
    for (int j = 0; j < 4; j++) {
        int i = base + j;
        if (i < n) { int v = row[i] + off; row[i] = v; cursor[i] = v; }
    }
    if (b == 0 && t == 0) row[n] = E;
}

// ---------------- CSR fill ----------------
__global__ void fill_kernel(const int* __restrict__ src, const int* __restrict__ dst,
                            int* __restrict__ cursor, int* __restrict__ csr_src, int E) {
    int e = blockIdx.x * blockDim.x + threadIdx.x;
    if (e < E) {
        int pos = atomicAdd(&cursor[dst[e]], 1);
        csr_src[pos] = src[e];
    }
}

// ---------------- tiled register-blocked GEMM: hsb[v,:] = bf16((X[v,:] @ W) * dis[v]) ------------
template <int K>
__global__ __launch_bounds__(256) void gemm_tile(const float* __restrict__ X,
                                                 const float* __restrict__ W,
                                                 const float* __restrict__ dis,
                                                 unsigned short* __restrict__ outb, int n) {
    constexpr int KC = 32;
    __shared__ float asT[KC][68];
    __shared__ float bs[KC * HID];
    const int t = threadIdx.x;
    const int tx = t & 31;   // col quad
    const int ty = t >> 5;   // row group
    const int row0 = blockIdx.x * 64;

    float4 acc[8];
#pragma unroll
    for (int j = 0; j < 8; j++) acc[j] = make_float4(0.f, 0.f, 0.f, 0.f);

    const int ar = t >> 3;
    const int af = t & 7;

    for (int k0 = 0; k0 < K; k0 += KC) {
#pragma unroll
        for (int half = 0; half < 2; half++) {
            const int r = ar + half * 32;
            const int gr = row0 + r;
            float4 a = make_float4(0.f, 0.f, 0.f, 0.f);
            if (gr < n) a = *(const float4*)&X[(long)gr * K + k0 + af * 4];
            asT[af * 4 + 0][r] = a.x;
            asT[af * 4 + 1][r] = a.y;
            asT[af * 4 + 2][r] = a.z;
            asT[af * 4 + 3][r] = a.w;
        }
        {
            const float4* wp = (const float4*)&W[(long)k0 * HID];
            float4* bp = (float4*)bs;
#pragma unroll
            for (int i = 0; i < 4; i++) bp[t + i * 256] = wp[t + i * 256];
        }
        __syncthreads();
#pragma unroll 8
        for (int kk = 0; kk < KC; kk++) {
            const float4 a0 = *(const float4*)&asT[kk][ty * 8];
            const float4 a1 = *(const float4*)&asT[kk][ty * 8 + 4];
            const float4 b  = *(const float4*)&bs[kk * HID + tx * 4];
            acc[0].x = fmaf(a0.x, b.x, acc[0].x); acc[0].y = fmaf(a0.x, b.y, acc[0].y);
            acc[0].z = fmaf(a0.x, b.z, acc[0].z); acc[0].w = fmaf(a0.x, b.w, acc[0].w);
            acc[1].x = fmaf(a0.y, b.x, acc[1].x); acc[1].y = fmaf(a0.y, b.y, acc[1].y);
            acc[1].z = fmaf(a0.y, b.z, acc[1].z); acc[1].w = fmaf(a0.y, b.w, acc[1].w);
            acc[2].x = fmaf(a0.z, b.x, acc[2].x); acc[2].y = fmaf(a0.z, b.y, acc[2].y);
            acc[2].z = fmaf(a0.z, b.z, acc[2].z); acc[2].w = fmaf(a0.z, b.w, acc[2].w);
            acc[3].x = fmaf(a0.w, b.x, acc[3].x); acc[3].y = fmaf(a0.w, b.y, acc[3].y);
            acc[3].z = fmaf(a0.w, b.z, acc[3].z); acc[3].w = fmaf(a0.w, b.w, acc[3].w);
            acc[4].x = fmaf(a1.x, b.x, acc[4].x); acc[4].y = fmaf(a1.x, b.y, acc[4].y);
            acc[4].z = fmaf(a1.x, b.z, acc[4].z); acc[4].w = fmaf(a1.x, b.w, acc[4].w);
            acc[5].x = fmaf(a1.y, b.x, acc[5].x); acc[5].y = fmaf(a1.y, b.y, acc[5].y);
            acc[5].z = fmaf(a1.y, b.z, acc[5].z); acc[5].w = fmaf(a1.y, b.w, acc[5].w);
            acc[6].x = fmaf(a1.z, b.x, acc[6].x); acc[6].y = fmaf(a1.z, b.y, acc[6].y);
            acc[6].z = fmaf(a1.z, b.z, acc[6].z); acc[6].w = fmaf(a1.z, b.w, acc[6].w);
            acc[7].x = fmaf(a1.w, b.x, acc[7].x); acc[7].y = fmaf(a1.w, b.y, acc[7].y);
            acc[7].z = fmaf(a1.w, b.z, acc[7].z); acc[7].w = fmaf(a1.w, b.w, acc[7].w);
        }
        __syncthreads();
    }

#pragma unroll
    for (int j = 0; j < 8; j++) {
        const int v = row0 + ty * 8 + j;
        if (v < n) {
            const float dv = dis[v];
            ushort4 r;
            r.x = f2bf(acc[j].x * dv);
            r.y = f2bf(acc[j].y * dv);
            r.z = f2bf(acc[j].z * dv);
            r.w = f2bf(acc[j].w * dv);
            *(ushort4*)&outb[(long)v * HID + tx * 4] = r;
        }
    }
}

// ---------------- gather aggregation + finalize (+ optional fused pool) ----------------
// One 64-lane wave per dst node; 16 lanes per edge (lane covers 8 bf16 cols = 16 B),
// 4 edges per pass, 8 passes unrolled -> up to 8 outstanding dwordx4 gathers per lane.
// No __shfl in the inner loop; cross-sub partial sums folded once per node.
template <bool POOL>
__global__ __launch_bounds__(256) void agg_kernel(const unsigned short* __restrict__ hsb,
                                                  const int* __restrict__ csr_src,
                                                  const int* __restrict__ row,
                                                  const float* __restrict__ dis,
                                                  const float* __restrict__ bias,
                                                  const int* __restrict__ batch,
                                                  float* __restrict__ out,
                                                  float* __restrict__ sums,
                                                  int* __restrict__ cnt, int n) {
    const int v = blockIdx.x * 4 + (threadIdx.x >> 6);
    if (v >= n) return;
    const int lane = threadIdx.x & 63;
    const int sub = lane >> 4;      // edge slot within pass (0..3)
    const int lc  = lane & 15;      // 16 lanes per edge; cols 8*lc .. 8*lc+7

    const int rs = row[v];
    const int re = row[v + 1];

    float acc[8];
#pragma unroll
    for (int i = 0; i < 8; i++) acc[i] = 0.f;

    for (int base = rs; base < re; base += 32) {
        uint4 w[8];
        int vld[8];
#pragma unroll
        for (int p = 0; p < 8; p++) {
            const int pe = base + p * 4;
            if (pe < re) {                       // wave-uniform guard
                const int ei = pe + sub;
                const int idx = csr_src[(ei < re) ? ei : (re - 1)];
                w[p] = *(const uint4*)&hsb[(long)idx * HID + (lc << 3)];
                vld[p] = (ei < re);
            } else {
                w[p] = make_uint4(0u, 0u, 0u, 0u);
                vld[p] = 0;
            }
        }
#pragma unroll
        for (int p = 0; p < 8; p++) {
            if (vld[p]) {
                const uint4 ww = w[p];
                acc[0] += bf2f(ww.x & 0xffffu); acc[1] += bf2f(ww.x >> 16);
                acc[2] += bf2f(ww.y & 0xffffu); acc[3] += bf2f(ww.y >> 16);
                acc[4] += bf2f(ww.z & 0xffffu); acc[5] += bf2f(ww.z >> 16);
                acc[6] += bf2f(ww.w & 0xffffu); acc[7] += bf2f(ww.w >> 16);
            }
        }
    }

    // fold the 4 sub-groups (lanes differing in bits 4..5, same lc)
#pragma unroll
    for (int i = 0; i < 8; i++) {
        acc[i] += __shfl_xor(acc[i], 16, 64);
        acc[i] += __shfl_xor(acc[i], 32, 64);
    }

    // each lane now owns cols col, col+1 where col = 8*lc + 2*sub
    const int col = (lc << 3) + (sub << 1);
    const unsigned int selfm = *(const unsigned int*)&hsb[(long)v * HID + col];
    const float sx = acc[(sub << 1) + 0] + bf2f(selfm & 0xffffu);
    const float sy = acc[(sub << 1) + 1] + bf2f(selfm >> 16);
    const float dv = dis[v];
    const float rx = fmaxf(fmaf(dv, sx, bias[col]), 0.f);
    const float ry = fmaxf(fmaf(dv, sy, bias[col + 1]), 0.f);
    if (POOL) {
        const int g = batch[v];
        unsafeAtomicAdd(&sums[g * HID + col], rx);
        unsafeAtomicAdd(&sums[g * HID + col + 1], ry);
        if (lane == 0) atomicAdd(&cnt[g], 1);
    } else {
        float2 r; r.x = rx; r.y = ry;
        *(float2*)&out[(long)v * HID + col] = r;
    }
}

// ---------------- mean + MLP head ----------------
__global__ __launch_bounds__(64) void mlp_kernel(const float* __restrict__ sums,
                                                 const int* __restrict__ cnt,
                                                 const float* __restrict__ Wl1,
                                                 const float* __restrict__ bl1,
                                                 const float* __restrict__ Wl2,
                                                 const float* __restrict__ bl2,
                                                 float* __restrict__ out) {
    const int g = blockIdx.x, t = threadIdx.x;
    __shared__ float mean[HID];
    __shared__ float hid[64];
    const float c = fmaxf((float)cnt[g], 1.0f);
    mean[t] = sums[g * HID + t] / c;
    mean[t + 64] = sums[g * HID + 64 + t] / c;
    __syncthreads();
    float acc = bl1[t];
#pragma unroll 4
    for (int k = 0; k < HID; k++) acc = fmaf(mean[k], Wl1[k * 64 + t], acc);
    hid[t] = fmaxf(acc, 0.f);
    __syncthreads();
    if (t < 5) {
        float a = bl2[t];
#pragma unroll 4
        for (int k = 0; k < 64; k++) a = fmaf(hid[k], Wl2[k * 5 + t], a);
        out[g * 5 + t] = 1.f / (1.f + expf(-a));
    }
}

extern "C" void kernel_launch(void* const* d_in, const int* in_sizes, int n_in,
                              void* d_out, int out_size, void* d_ws, size_t ws_size,
                              hipStream_t stream) {
    const float* x   = (const float*)d_in[0];
    const int* ei    = (const int*)d_in[1];
    const int* batch = (const int*)d_in[2];
    const float* W1  = (const float*)d_in[3];
    const float* b1  = (const float*)d_in[4];
    const float* W2  = (const float*)d_in[5];
    const float* b2  = (const float*)d_in[6];
    const float* Wl1 = (const float*)d_in[7];
    const float* bl1 = (const float*)d_in[8];
    const float* Wl2 = (const float*)d_in[9];
    const float* bl2 = (const float*)d_in[10];
    float* out = (float*)d_out;

    const int n = in_sizes[0] / IN_DIM;       // 50000
    const int E = in_sizes[1] / 2;            // 1600000
    const int* src = ei;
    const int* dst = ei + E;

    char* ws = (char*)d_ws;
    size_t off = 0;
    auto alloc = [&](size_t bytes) {
        void* p = ws + off;
        off = (off + bytes + 255) & ~(size_t)255;
        return p;
    };
    int*   deg       = (int*)alloc((size_t)n * 4);
    float* dis       = (float*)alloc((size_t)n * 4);
    int*   row       = (int*)alloc((size_t)(n + 1) * 4);
    int*   cursor    = (int*)alloc((size_t)n * 4);
    int*   csr_src   = (int*)alloc((size_t)E * 4);
    int*   blockSums = (int*)alloc(256 * 4);
    unsigned short* hsb = (unsigned short*)alloc((size_t)n * HID * 2);  // bf16 messages
    float* buf1 = (float*)alloc((size_t)n * HID * 4);                    // fp32 inter-layer h
    float* sums = (float*)alloc((size_t)NGRAPH * HID * 4);
    int*   cnt  = (int*)alloc((size_t)NGRAPH * 4);
    (void)ws_size;

    const int nb = (n + 1023) / 1024;
    const int gemmBlocks = (n + 63) / 64;
    const int aggBlocks  = (n + 3) / 4;

    // --- degree / norm / CSR ---
    hipMemsetAsync(deg, 0, (size_t)n * 4, stream);
    deg_kernel<<<(E + 255) / 256, 256, 0, stream>>>(dst, deg, E);
    dis_kernel<<<(n + 255) / 256, 256, 0, stream>>>(deg, dis, n);
    scan_part<<<nb, 256, 0, stream>>>(deg, row, blockSums, n);
    scan_tops<<<1, 64, 0, stream>>>(blockSums, nb);
    scan_add<<<nb, 256, 0, stream>>>(row, cursor, blockSums, n, E);
    fill_kernel<<<(E + 255) / 256, 256, 0, stream>>>(src, dst, cursor, csr_src, E);

    // --- conv1 ---
    gemm_tile<IN_DIM><<<gemmBlocks, 256, 0, stream>>>(x, W1, dis, hsb, n);
    agg_kernel<false><<<aggBlocks, 256, 0, stream>>>(hsb, csr_src, row, dis, b1, batch,
                                                     buf1, nullptr, nullptr, n);

    // --- conv2 (pool fused) ---
    gemm_tile<HID><<<gemmBlocks, 256, 0, stream>>>(buf1, W2, dis, hsb, n);
    hipMemsetAsync(sums, 0, (size_t)NGRAPH * HID * 4, stream);
    hipMemsetAsync(cnt, 0, (size_t)NGRAPH * 4, stream);
    agg_kernel<true><<<aggBlocks, 256, 0, stream>>>(hsb, csr_src, row, dis, b2, batch,
                                                    nullptr, sums, cnt, n);

    // --- head ---
    mlp_kernel<<<NGRAPH, 64, 0, stream>>>(sums, cnt, Wl1, bl1, Wl2, bl2, out);
}

// Round 7
// 616.899 us; speedup vs baseline: 1.0667x; 1.0667x over previous
//
#include <hip/hip_runtime.h>
#include <hip/hip_bf16.h>

#define HID 128
#define NGRAPH 512
#define IN_DIM 384

typedef __attribute__((ext_vector_type(2))) float f32x2;

// ---------------- degree ----------------
__global__ void deg_kernel(const int* __restrict__ dst, int* __restrict__ deg, int E) {
    int e = blockIdx.x * blockDim.x + threadIdx.x;
    if (e < E) atomicAdd(&deg[dst[e]], 1);
}

__global__ void dis_kernel(const int* __restrict__ deg, float* __restrict__ dis, int n) {
    int v = blockIdx.x * blockDim.x + threadIdx.x;
    if (v < n) dis[v] = rsqrtf((float)(deg[v] + 1));  // +1 = self-loop
}

// ---------------- exclusive scan of deg -> row_start ----------------
__global__ __launch_bounds__(256) void scan_part(const int* __restrict__ deg, int* __restrict__ row,
                                                 int* __restrict__ blockSums, int n) {
    __shared__ int ts[256];
    const int b = blockIdx.x, t = threadIdx.x;
    const int base = b * 1024 + t * 4;
    int v0 = (base + 0 < n) ? deg[base + 0] : 0;
    int v1 = (base + 1 < n) ? deg[base + 1] : 0;
    int v2 = (base + 2 < n) ? deg[base + 2] : 0;
    int v3 = (base + 3 < n) ? deg[base + 3] : 0;
    const int s = v0 + v1 + v2 + v3;
    ts[t] = s;
    __syncthreads();
    for (int off = 1; off < 256; off <<= 1) {
        int x = (t >= off) ? ts[t - off] : 0;
        __syncthreads();
        ts[t] += x;
        __syncthreads();
    }
    int p = ts[t] - s;
    if (base + 0 < n) { row[base + 0] = p; p += v0; }
    if (base + 1 < n) { row[base + 1] = p; p += v1; }
    if (base + 2 < n) { row[base + 2] = p; p += v2; }
    if (base + 3 < n) { row[base + 3] = p; }
    if (t == 255) blockSums[b] = ts[255];
}

__global__ void scan_tops(int* __restrict__ blockSums, int nb) {
    if (threadIdx.x == 0 && blockIdx.x == 0) {
        int acc = 0;
        for (int i = 0; i < nb; i++) { int v = blockSums[i]; blockSums[i] = acc; acc += v; }
    }
}

__global__ __launch_bounds__(256) void scan_add(int* __restrict__ row, int* __restrict__ cursor,
                                                const int* __restrict__ blockSums, int n, int E) {
    const int b = blockIdx.x, t = threadIdx.x;
    const int off = blockSums[b];
    const int base = b * 1024 + t * 4;
#pragma unroll
    for (int j = 0; j < 4; j++) {
        int i = base + j;
        if (i < n) { int v = row[i] + off; row[i] = v; cursor[i] = v; }
    }
    if (b == 0 && t == 0) row[n] = E;
}

// ---------------- CSR fill ----------------
__global__ void fill_kernel(const int* __restrict__ src, const int* __restrict__ dst,
                            int* __restrict__ cursor, int* __restrict__ csr_src, int E) {
    int e = blockIdx.x * blockDim.x + threadIdx.x;
    if (e < E) {
        int pos = atomicAdd(&cursor[dst[e]], 1);
        csr_src[pos] = src[e];
    }
}

// ---- tiled register-blocked GEMM: hs8[v,:] = fp8_e4m3( (X[v,:] @ W) * dis[v] * 8 ) ----
template <int K>
__global__ __launch_bounds__(256) void gemm_tile(const float* __restrict__ X,
                                                 const float* __restrict__ W,
                                                 const float* __restrict__ dis,
                                                 unsigned int* __restrict__ out8, int n) {
    constexpr int KC = 32;
    __shared__ float asT[KC][68];
    __shared__ float bs[KC * HID];
    const int t = threadIdx.x;
    const int tx = t & 31;   // col quad
    const int ty = t >> 5;   // row group
    const int row0 = blockIdx.x * 64;

    float4 acc[8];
#pragma unroll
    for (int j = 0; j < 8; j++) acc[j] = make_float4(0.f, 0.f, 0.f, 0.f);

    const int ar = t >> 3;
    const int af = t & 7;

    for (int k0 = 0; k0 < K; k0 += KC) {
#pragma unroll
        for (int half = 0; half < 2; half++) {
            const int r = ar + half * 32;
            const int gr = row0 + r;
            float4 a = make_float4(0.f, 0.f, 0.f, 0.f);
            if (gr < n) a = *(const float4*)&X[(long)gr * K + k0 + af * 4];
            asT[af * 4 + 0][r] = a.x;
            asT[af * 4 + 1][r] = a.y;
            asT[af * 4 + 2][r] = a.z;
            asT[af * 4 + 3][r] = a.w;
        }
        {
            const float4* wp = (const float4*)&W[(long)k0 * HID];
            float4* bp = (float4*)bs;
#pragma unroll
            for (int i = 0; i < 4; i++) bp[t + i * 256] = wp[t + i * 256];
        }
        __syncthreads();
#pragma unroll 8
        for (int kk = 0; kk < KC; kk++) {
            const float4 a0 = *(const float4*)&asT[kk][ty * 8];
            const float4 a1 = *(const float4*)&asT[kk][ty * 8 + 4];
            const float4 b  = *(const float4*)&bs[kk * HID + tx * 4];
            acc[0].x = fmaf(a0.x, b.x, acc[0].x); acc[0].y = fmaf(a0.x, b.y, acc[0].y);
            acc[0].z = fmaf(a0.x, b.z, acc[0].z); acc[0].w = fmaf(a0.x, b.w, acc[0].w);
            acc[1].x = fmaf(a0.y, b.x, acc[1].x); acc[1].y = fmaf(a0.y, b.y, acc[1].y);
            acc[1].z = fmaf(a0.y, b.z, acc[1].z); acc[1].w = fmaf(a0.y, b.w, acc[1].w);
            acc[2].x = fmaf(a0.z, b.x, acc[2].x); acc[2].y = fmaf(a0.z, b.y, acc[2].y);
            acc[2].z = fmaf(a0.z, b.z, acc[2].z); acc[2].w = fmaf(a0.z, b.w, acc[2].w);
            acc[3].x = fmaf(a0.w, b.x, acc[3].x); acc[3].y = fmaf(a0.w, b.y, acc[3].y);
            acc[3].z = fmaf(a0.w, b.z, acc[3].z); acc[3].w = fmaf(a0.w, b.w, acc[3].w);
            acc[4].x = fmaf(a1.x, b.x, acc[4].x); acc[4].y = fmaf(a1.x, b.y, acc[4].y);
            acc[4].z = fmaf(a1.x, b.z, acc[4].z); acc[4].w = fmaf(a1.x, b.w, acc[4].w);
            acc[5].x = fmaf(a1.y, b.x, acc[5].x); acc[5].y = fmaf(a1.y, b.y, acc[5].y);
            acc[5].z = fmaf(a1.y, b.z, acc[5].z); acc[5].w = fmaf(a1.y, b.w, acc[5].w);
            acc[6].x = fmaf(a1.z, b.x, acc[6].x); acc[6].y = fmaf(a1.z, b.y, acc[6].y);
            acc[6].z = fmaf(a1.z, b.z, acc[6].z); acc[6].w = fmaf(a1.z, b.w, acc[6].w);
            acc[7].x = fmaf(a1.w, b.x, acc[7].x); acc[7].y = fmaf(a1.w, b.y, acc[7].y);
            acc[7].z = fmaf(a1.w, b.z, acc[7].z); acc[7].w = fmaf(a1.w, b.w, acc[7].w);
        }
        __syncthreads();
    }

#pragma unroll
    for (int j = 0; j < 8; j++) {
        const int v = row0 + ty * 8 + j;
        if (v < n) {
            const float s = dis[v] * 8.0f;   // x8 keeps layer-2 messages out of e4m3 subnormals
            int w01 = __builtin_amdgcn_cvt_pk_fp8_f32(acc[j].x * s, acc[j].y * s, 0, false);
            int w   = __builtin_amdgcn_cvt_pk_fp8_f32(acc[j].z * s, acc[j].w * s, w01, true);
            out8[(long)v * (HID / 4) + tx] = (unsigned int)w;
        }
    }
}

// ---------------- gather aggregation + finalize (+ optional fused pool) ----------------
// One 64-lane wave per dst node; 8 lanes per edge (lane covers 16 fp8 cols = 16 B = the
// whole 128-B row across 8 lanes -> 1 cache line per edge). 8 edges per pass, 4 passes
// unrolled. Cross-sub fold via 3 shfl_xor steps; each lane then owns 2 cols.
template <bool POOL>
__global__ __launch_bounds__(256) void agg_kernel(const unsigned char* __restrict__ hs8,
                                                  const int* __restrict__ csr_src,
                                                  const int* __restrict__ row,
                                                  const float* __restrict__ dis,
                                                  const float* __restrict__ bias,
                                                  const int* __restrict__ batch,
                                                  float* __restrict__ out,
                                                  float* __restrict__ sums,
                                                  int* __restrict__ cnt, int n) {
    const int v = blockIdx.x * 4 + (threadIdx.x >> 6);
    if (v >= n) return;
    const int lane = threadIdx.x & 63;
    const int sub = lane >> 3;      // edge slot within pass (0..7)
    const int lc  = lane & 7;       // 16-byte chunk within row; cols 16*lc .. 16*lc+15

    const int rs = row[v];
    const int re = row[v + 1];

    float acc[16];
#pragma unroll
    for (int i = 0; i < 16; i++) acc[i] = 0.f;

    for (int base = rs; base < re; base += 32) {
        uint4 w[4];
        int vld[4];
#pragma unroll
        for (int p = 0; p < 4; p++) {
            const int pe = base + p * 8;
            if (pe < re) {                       // wave-uniform guard
                const int ei = pe + sub;
                const int idx = csr_src[(ei < re) ? ei : (re - 1)];
                w[p] = *(const uint4*)&hs8[(long)idx * HID + (lc << 4)];
                vld[p] = (ei < re);
            } else {
                w[p] = make_uint4(0u, 0u, 0u, 0u);
                vld[p] = 0;
            }
        }
#pragma unroll
        for (int p = 0; p < 4; p++) {
            if (vld[p]) {
                const uint4 ww = w[p];
                f32x2 u;
                u = __builtin_amdgcn_cvt_pk_f32_fp8(ww.x, false); acc[0]  += u.x; acc[1]  += u.y;
                u = __builtin_amdgcn_cvt_pk_f32_fp8(ww.x, true);  acc[2]  += u.x; acc[3]  += u.y;
                u = __builtin_amdgcn_cvt_pk_f32_fp8(ww.y, false); acc[4]  += u.x; acc[5]  += u.y;
                u = __builtin_amdgcn_cvt_pk_f32_fp8(ww.y, true);  acc[6]  += u.x; acc[7]  += u.y;
                u = __builtin_amdgcn_cvt_pk_f32_fp8(ww.z, false); acc[8]  += u.x; acc[9]  += u.y;
                u = __builtin_amdgcn_cvt_pk_f32_fp8(ww.z, true);  acc[10] += u.x; acc[11] += u.y;
                u = __builtin_amdgcn_cvt_pk_f32_fp8(ww.w, false); acc[12] += u.x; acc[13] += u.y;
                u = __builtin_amdgcn_cvt_pk_f32_fp8(ww.w, true);  acc[14] += u.x; acc[15] += u.y;
            }
        }
    }

    // fold the 8 sub-groups (lanes differing in bits 3..5, same lc)
#pragma unroll
    for (int i = 0; i < 16; i++) {
        acc[i] += __shfl_xor(acc[i], 8, 64);
        acc[i] += __shfl_xor(acc[i], 16, 64);
        acc[i] += __shfl_xor(acc[i], 32, 64);
    }

    // each lane now owns cols col, col+1 where col = 16*lc + 2*sub
    const int col = (lc << 4) + (sub << 1);
    const unsigned short selfw = *(const unsigned short*)&hs8[(long)v * HID + col];
    f32x2 sf = __builtin_amdgcn_cvt_pk_f32_fp8((unsigned int)selfw, false);
    const float sx = acc[(sub << 1) + 0] + sf.x;
    const float sy = acc[(sub << 1) + 1] + sf.y;
    const float dv = dis[v] * 0.125f;   // undo the x8 message scale
    const float rx = fmaxf(fmaf(dv, sx, bias[col]), 0.f);
    const float ry = fmaxf(fmaf(dv, sy, bias[col + 1]), 0.f);
    if (POOL) {
        const int g = batch[v];
        unsafeAtomicAdd(&sums[g * HID + col], rx);
        unsafeAtomicAdd(&sums[g * HID + col + 1], ry);
        if (lane == 0) atomicAdd(&cnt[g], 1);
    } else {
        float2 r; r.x = rx; r.y = ry;
        *(float2*)&out[(long)v * HID + col] = r;
    }
}

// ---------------- mean + MLP head ----------------
__global__ __launch_bounds__(64) void mlp_kernel(const float* __restrict__ sums,
                                                 const int* __restrict__ cnt,
                                                 const float* __restrict__ Wl1,
                                                 const float* __restrict__ bl1,
                                                 const float* __restrict__ Wl2,
                                                 const float* __restrict__ bl2,
                                                 float* __restrict__ out) {
    const int g = blockIdx.x, t = threadIdx.x;
    __shared__ float mean[HID];
    __shared__ float hid[64];
    const float c = fmaxf((float)cnt[g], 1.0f);
    mean[t] = sums[g * HID + t] / c;
    mean[t + 64] = sums[g * HID + 64 + t] / c;
    __syncthreads();
    float acc = bl1[t];
#pragma unroll 4
    for (int k = 0; k < HID; k++) acc = fmaf(mean[k], Wl1[k * 64 + t], acc);
    hid[t] = fmaxf(acc, 0.f);
    __syncthreads();
    if (t < 5) {
        float a = bl2[t];
#pragma unroll 4
        for (int k = 0; k < 64; k++) a = fmaf(hid[k], Wl2[k * 5 + t], a);
        out[g * 5 + t] = 1.f / (1.f + expf(-a));
    }
}

extern "C" void kernel_launch(void* const* d_in, const int* in_sizes, int n_in,
                              void* d_out, int out_size, void* d_ws, size_t ws_size,
                              hipStream_t stream) {
    const float* x   = (const float*)d_in[0];
    const int* ei    = (const int*)d_in[1];
    const int* batch = (const int*)d_in[2];
    const float* W1  = (const float*)d_in[3];
    const float* b1  = (const float*)d_in[4];
    const float* W2  = (const float*)d_in[5];
    const float* b2  = (const float*)d_in[6];
    const float* Wl1 = (const float*)d_in[7];
    const float* bl1 = (const float*)d_in[8];
    const float* Wl2 = (const float*)d_in[9];
    const float* bl2 = (const float*)d_in[10];
    float* out = (float*)d_out;

    const int n = in_sizes[0] / IN_DIM;       // 50000
    const int E = in_sizes[1] / 2;            // 1600000
    const int* src = ei;
    const int* dst = ei + E;

    char* ws = (char*)d_ws;
    size_t off = 0;
    auto alloc = [&](size_t bytes) {
        void* p = ws + off;
        off = (off + bytes + 255) & ~(size_t)255;
        return p;
    };
    int*   deg       = (int*)alloc((size_t)n * 4);
    float* dis       = (float*)alloc((size_t)n * 4);
    int*   row       = (int*)alloc((size_t)(n + 1) * 4);
    int*   cursor    = (int*)alloc((size_t)n * 4);
    int*   csr_src   = (int*)alloc((size_t)E * 4);
    int*   blockSums = (int*)alloc(256 * 4);
    unsigned char* hs8 = (unsigned char*)alloc((size_t)n * HID);       // fp8 messages
    float* buf1 = (float*)alloc((size_t)n * HID * 4);                  // fp32 inter-layer h
    float* sums = (float*)alloc((size_t)NGRAPH * HID * 4);
    int*   cnt  = (int*)alloc((size_t)NGRAPH * 4);
    (void)ws_size;

    const int nb = (n + 1023) / 1024;
    const int gemmBlocks = (n + 63) / 64;
    const int aggBlocks  = (n + 3) / 4;

    // --- degree / norm / CSR ---
    hipMemsetAsync(deg, 0, (size_t)n * 4, stream);
    deg_kernel<<<(E + 255) / 256, 256, 0, stream>>>(dst, deg, E);
    dis_kernel<<<(n + 255) / 256, 256, 0, stream>>>(deg, dis, n);
    scan_part<<<nb, 256, 0, stream>>>(deg, row, blockSums, n);
    scan_tops<<<1, 64, 0, stream>>>(blockSums, nb);
    scan_add<<<nb, 256, 0, stream>>>(row, cursor, blockSums, n, E);
    fill_kernel<<<(E + 255) / 256, 256, 0, stream>>>(src, dst, cursor, csr_src, E);

    // --- conv1 ---
    gemm_tile<IN_DIM><<<gemmBlocks, 256, 0, stream>>>(x, W1, dis, (unsigned int*)hs8, n);
    agg_kernel<false><<<aggBlocks, 256, 0, stream>>>(hs8, csr_src, row, dis, b1, batch,
                                                     buf1, nullptr, nullptr, n);

    // --- conv2 (pool fused) ---
    gemm_tile<HID><<<gemmBlocks, 256, 0, stream>>>(buf1, W2, dis, (unsigned int*)hs8, n);
    hipMemsetAsync(sums, 0, (size_t)NGRAPH * HID * 4, stream);
    hipMemsetAsync(cnt, 0, (size_t)NGRAPH * 4, stream);
    agg_kernel<true><<<aggBlocks, 256, 0, stream>>>(hs8, csr_src, row, dis, b2, batch,
                                                    nullptr, sums, cnt, n);

    // --- head ---
    mlp_kernel<<<NGRAPH, 64, 0, stream>>>(sums, cnt, Wl1, bl1, Wl2, bl2, out);
}